// Round 9
// baseline (6633.727 us; speedup 1.0000x reference)
//
#include <hip/hip_runtime.h>
#include <math.h>

// ---------------- workspace layout (float offsets) ----------------
#define OFF_CW   0L         // conv w [l8][w8][k9][i128][o16]   = 1179648
#define OFF_FUS  1179648L   // fus  w [wv16][i1024][o16]        = 262144
#define OFF_W1G  1441792L   // W1G  [c256][o512]                = 131072
#define OFF_W1H  1572864L   // W1H  [wv16][i1024][o32]          = 524288
#define OFF_W2S  2097152L   // W2S  [c4][wv16][i128][o4]        = 32768
#define OFF_DYN  2129920L   // dynamic: states [C][1024][128]
#define REPACK_N 2129920L

__global__ void k_repack(const float* __restrict__ head_w, const float* __restrict__ res_w,
                         const float* __restrict__ fusion_w,
                         const float* __restrict__ pred1_w, const float* __restrict__ cls1_w,
                         const float* __restrict__ pred2_w, const float* __restrict__ cls2_w,
                         float* __restrict__ ws) {
  long j = (long)blockIdx.x * 256 + threadIdx.x;
  if (j >= REPACK_N) return;
  if (j < OFF_FUS) {                       // CW[l][w][k][i][o16]
    long q = j;
    int o = (int)(q & 15); q >>= 4;
    int i = (int)(q & 127); q >>= 7;
    int k = (int)(q % 9); long q2 = q / 9;
    int w = (int)(q2 & 7), l = (int)(q2 >> 3);
    int og = w * 16 + o;
    float v;
    if (l == 0) v = (i < 67) ? head_w[(og * 67 + i) * 9 + k] : 0.f;
    else        v = res_w[(((l - 1) * 128 + og) * 128 + i) * 9 + k];
    ws[j] = v;
  } else if (j < OFF_W1G) {                // FUS[wv][i][o16]
    long q = j - OFF_FUS;
    int o = (int)(q & 15), i = (int)((q >> 4) & 1023), wv = (int)(q >> 14);
    ws[j] = fusion_w[(long)(wv * 16 + o) * 1024 + i];
  } else if (j < OFF_W1H) {                // W1G[c][o]
    long q = j - OFF_W1G; int o = (int)(q & 511); int c = (int)(q >> 9);
    ws[j] = (o < 256) ? pred1_w[(long)o * 1280 + c] : cls1_w[(long)(o - 256) * 1280 + c];
  } else if (j < OFF_W2S) {                // W1H[wv][i][o32]
    long q = j - OFF_W1H;
    int o = (int)(q & 31), i = (int)((q >> 5) & 1023), wv = (int)(q >> 15);
    int ho = wv * 32 + o, c = 256 + i;
    ws[j] = (ho < 256) ? pred1_w[(long)ho * 1280 + c] : cls1_w[(long)(ho - 256) * 1280 + c];
  } else {                                 // W2S[c][wv][i][o4]
    long q = j - OFF_W2S;
    int o = (int)(q & 3), i = (int)((q >> 2) & 127), wv = (int)((q >> 9) & 15), c = (int)(q >> 13);
    int jg = wv * 4 + o;
    ws[j] = (c < 2) ? pred2_w[jg * 256 + c * 128 + i] : cls2_w[jg * 256 + (c - 2) * 128 + i];
  }
}

// =============== K1: gather + 8-layer conv chain + states (512 thr, 64KB LDS, 2 blk/CU) ===============
// 8 waves x 16 out-ch; lane po owns positions {po, po+64} (stride-1 LDS, conflict-free).
// Per (k,i) slot: 1 s_load_dwordx16 (weights, SGPR) + 2 ds_read_b32 + 32 FMAs -> VALU-bound mix.
__global__ __launch_bounds__(512) __attribute__((amdgpu_waves_per_eu(4)))
void k_conv(const float* __restrict__ cnn, const float* __restrict__ i_it,
            const float* __restrict__ c_it, const float* __restrict__ cls_in,
            const int* __restrict__ ind,
            const float* __restrict__ CW,
            const float* __restrict__ head_b, const float* __restrict__ res_b,
            float* __restrict__ states, int p0) {
  __shared__ float sx[16384];    // [128 ch][128 pos] 64 KB
  const int ln = blockIdx.x, n = p0 + ln, t = threadIdx.x;
  const int po = t & 63;
  const int wv = __builtin_amdgcn_readfirstlane(t >> 6);   // 0..7
  const int ow = wv * 16;

  // ---- bilinear gather (4 groups x 16 channels) ----
  {
    const int p4 = t & 127, og4 = t >> 7;   // og4 in 0..3
    const float gx = i_it[((long)n * 128 + p4) * 2 + 0] - 0.5f;
    const float gy = i_it[((long)n * 128 + p4) * 2 + 1] - 0.5f;
    const float fx = floorf(gx), fy = floorf(gy);
    const float wx = gx - fx, wy = gy - fy;
    const int x0 = (int)fx, y0 = (int)fy, x1 = x0 + 1, y1 = y0 + 1;
    const bool vx0 = (x0 >= 0) & (x0 < 128), vx1 = (x1 >= 0) & (x1 < 128);
    const bool vy0 = (y0 >= 0) & (y0 < 128), vy1 = (y1 >= 0) & (y1 < 128);
    const int x0c = min(max(x0, 0), 127), x1c = min(max(x1, 0), 127);
    const int y0c = min(max(y0, 0), 127), y1c = min(max(y1, 0), 127);
    const float w00 = (vx0 && vy0) ? (1.f - wx) * (1.f - wy) : 0.f;
    const float w01 = (vx1 && vy0) ? wx * (1.f - wy) : 0.f;
    const float w10 = (vx0 && vy1) ? (1.f - wx) * wy : 0.f;
    const float w11 = (vx1 && vy1) ? wx * wy : 0.f;
    const long base = (long)ind[n] * 64 * 16384;
    const int a00 = y0c * 128 + x0c, a01 = y0c * 128 + x1c;
    const int a10 = y1c * 128 + x0c, a11 = y1c * 128 + x1c;
    for (int cc = 0; cc < 16; cc++) {
      const int c = og4 * 16 + cc;
      const float* f = cnn + base + (long)c * 16384;
      sx[c * 128 + p4] = f[a00] * w00 + f[a01] * w01 + f[a10] * w10 + f[a11] * w11;
    }
    if (og4 == 0) {
      sx[64 * 128 + p4] = c_it[((long)n * 128 + p4) * 2 + 0] * 4.0f;
      sx[65 * 128 + p4] = c_it[((long)n * 128 + p4) * 2 + 1] * 4.0f;
      sx[66 * 128 + p4] = cls_in[(long)n * 128 + p4];
    }
  }
  for (int idx = t; idx < 61 * 128; idx += 512) sx[67 * 128 + idx] = 0.f;
  __syncthreads();

  float* st = states + (long)ln * 131072;

  for (int l = 0; l < 8; l++) {
    const int dil = (l >= 6) ? 4 : ((l >= 4) ? 2 : 1);
    const int ni = (l == 0) ? 68 : 128;    // head conv rows >=67 are zero
    float a0[16], a1[16];
    {
      const float* bsrc = (l == 0) ? (head_b + ow) : (res_b + (l - 1) * 128 + ow);
#pragma unroll
      for (int oo = 0; oo < 16; oo++) { a0[oo] = bsrc[oo]; a1[oo] = a0[oo]; }
    }
    const float* wl = CW + (long)(l * 8 + wv) * 18432;   // [k9][i128][o16]
    for (int k = 0; k < 9; k++) {
      const int xa0 = (po + (k - 4) * dil + 128) & 127;
      const int xa1 = xa0 ^ 64;
      const float* wk = wl + k * 2048;
#pragma unroll 4
      for (int i = 0; i < ni; i++) {
        const float xv0 = sx[i * 128 + xa0];
        const float xv1 = sx[i * 128 + xa1];
        const float* w = wk + i * 16;       // wave-uniform -> s_load_dwordx16
#pragma unroll
        for (int oo = 0; oo < 16; oo++) {
          a0[oo] = fmaf(w[oo], xv0, a0[oo]);
          a1[oo] = fmaf(w[oo], xv1, a1[oo]);
        }
      }
    }
    __syncthreads();           // conv reads of sx done
#pragma unroll
    for (int oo = 0; oo < 16; oo++) {
      const int o = ow + oo;
      float v0 = fmaxf(a0[oo], 0.f), v1 = fmaxf(a1[oo], 0.f);
      if (l > 0) { v0 += sx[o * 128 + po]; v1 += sx[o * 128 + po + 64]; }
      sx[o * 128 + po] = v0;
      sx[o * 128 + po + 64] = v1;
      st[(l * 128 + o) * 128 + po] = v0;
      st[(l * 128 + o) * 128 + po + 64] = v1;
    }
    __syncthreads();
  }
}

// =============== K2: fus+h1 GEMM + g + hg + pred2/cls2 + pred3/cls3 + NMS ===============
__global__ __launch_bounds__(1024) __attribute__((amdgpu_waves_per_eu(4)))
void k_h1t(const float* __restrict__ states, const float* __restrict__ W1H,
           const float* __restrict__ FUS, const float* __restrict__ fus_b,
           const float* __restrict__ W1G,
           const float* __restrict__ p1b, const float* __restrict__ c1b,
           const float* __restrict__ W2S,
           const float* __restrict__ p2b, const float* __restrict__ c2b,
           const float* __restrict__ p3w, const float* __restrict__ p3b,
           const float* __restrict__ c3w, const float* __restrict__ c3b,
           const float* __restrict__ i_it, float* __restrict__ out, int p0) {
  __shared__ float xb[2][2048];   // states staging, 16 ch x 128 pos, ping-pong (16 KB)
  __shared__ float hx[16384];     // g/hg scratch, then h1 chunks / h2 (64 KB)
  const int ln = blockIdx.x, n = p0 + ln, t = threadIdx.x;
  const int po = t & 63;
  const int wv = __builtin_amdgcn_readfirstlane(t >> 6);   // 0..15
  const float* xs = states + (long)ln * 131072;

  // ---- phase 1: h1 partial GEMM (32 rows/wave) + fus partial (16 outs/wave) ----
  float h0[32], h1v[32], f0[16], f1[16];
#pragma unroll
  for (int r = 0; r < 32; r++) { h0[r] = 0.f; h1v[r] = 0.f; }
#pragma unroll
  for (int r = 0; r < 16; r++) { f0[r] = 0.f; f1[r] = 0.f; }
  const float* wh_base = W1H + (long)wv * 32768;
  const float* wf_base = FUS + (long)wv * 16384;
  float2 px = ((const float2*)xs)[t];
  ((float2*)xb[0])[t] = px;
  __syncthreads();
  for (int c = 0; c < 64; c++) {
    if (c + 1 < 64) px = ((const float2*)(xs + (long)(c + 1) * 2048))[t];
    const float* xp = xb[c & 1];
    const float* wh = wh_base + c * 512;
    const float* wf = wf_base + c * 256;
#pragma unroll 4
    for (int i = 0; i < 16; i++) {
      const float xv0 = xp[i * 128 + po];
      const float xv1 = xp[i * 128 + po + 64];
      const float* w = wh + i * 32;          // s_load
      const float* f = wf + i * 16;          // s_load
#pragma unroll
      for (int r = 0; r < 32; r++) {
        h0[r] = fmaf(w[r], xv0, h0[r]);
        h1v[r] = fmaf(w[r], xv1, h1v[r]);
      }
#pragma unroll
      for (int r = 0; r < 16; r++) {
        f0[r] = fmaf(f[r], xv0, f0[r]);
        f1[r] = fmaf(f[r], xv1, f1[r]);
      }
    }
    if (c + 1 < 64) ((float2*)xb[(c + 1) & 1])[t] = px;
    __syncthreads();
  }

  // ---- g = max_p(fus) + fus_b ----
#pragma unroll
  for (int r = 0; r < 16; r++) {
    float m = fmaxf(f0[r], f1[r]);
#pragma unroll
    for (int s = 32; s > 0; s >>= 1) m = fmaxf(m, __shfl_xor(m, s, 64));
    if (po == 0) hx[wv * 16 + r] = m;
  }
  __syncthreads();
  if (t < 256) hx[256 + t] = hx[t] + fus_b[t];
  __syncthreads();
  // ---- hg[o] = bias + W1G[:,o].g (o = t < 512, coalesced) ----
  if (t < 512) {
    float s = (t < 256) ? p1b[t] : c1b[t - 256];
    const float* w = W1G + t;
#pragma unroll 8
    for (int c = 0; c < 256; c++) s = fmaf(w[(long)c * 512], hx[256 + c], s);
    hx[512 + t] = s;
  }
  __syncthreads();
#pragma unroll
  for (int r = 0; r < 32; r++) {
    const float bb = hx[512 + wv * 32 + r];   // wave-uniform LDS broadcast
    h0[r] = fmaxf(h0[r] + bb, 0.f);
    h1v[r] = fmaxf(h1v[r] + bb, 0.f);
  }

  // ---- phase 2: pred2/cls2 over 4 chunks of 128 h1 rows ----
  float ap0[4], ap1[4], ac0[4], ac1[4];
#pragma unroll
  for (int jj = 0; jj < 4; jj++) { ap0[jj] = 0.f; ap1[jj] = 0.f; ac0[jj] = 0.f; ac1[jj] = 0.f; }
#pragma unroll
  for (int c = 0; c < 4; c++) {
    __syncthreads();
    if ((wv >> 2) == c) {
#pragma unroll
      for (int r = 0; r < 32; r++) {
        const int row = (wv & 3) * 32 + r;
        hx[row * 128 + po] = h0[r];
        hx[row * 128 + po + 64] = h1v[r];
      }
    }
    __syncthreads();
    const float* w2 = W2S + (long)(c * 16 + wv) * 512;
#pragma unroll 4
    for (int i = 0; i < 128; i++) {
      const float xv0 = hx[i * 128 + po];
      const float xv1 = hx[i * 128 + po + 64];
      const float* w = w2 + i * 4;
      if (c < 2) {
#pragma unroll
        for (int jj = 0; jj < 4; jj++) {
          ap0[jj] = fmaf(w[jj], xv0, ap0[jj]);
          ap1[jj] = fmaf(w[jj], xv1, ap1[jj]);
        }
      } else {
#pragma unroll
        for (int jj = 0; jj < 4; jj++) {
          ac0[jj] = fmaf(w[jj], xv0, ac0[jj]);
          ac1[jj] = fmaf(w[jj], xv1, ac1[jj]);
        }
      }
    }
  }
  __syncthreads();
#pragma unroll
  for (int jj = 0; jj < 4; jj++) {   // h2 rows: j<64 pred2, j>=64 cls2
    const int j = wv * 4 + jj;
    hx[j * 128 + po] = fmaxf(ap0[jj] + p2b[j], 0.f);
    hx[j * 128 + po + 64] = fmaxf(ap1[jj] + p2b[j], 0.f);
    hx[(64 + j) * 128 + po] = fmaxf(ac0[jj] + c2b[j], 0.f);
    hx[(64 + j) * 128 + po + 64] = fmaxf(ac1[jj] + c2b[j], 0.f);
  }
  __syncthreads();

  // ---- phase 3: pred3/cls3 + outputs + NMS ----
  float sig = 0.f;
  const int pp = t & 127;
  if (t < 128) {
    float o0v = p3b[0], o1v = p3b[1], cv = c3b[0];
    for (int j = 0; j < 64; j++) {
      const float hp = hx[j * 128 + pp];
      const float hc = hx[(64 + j) * 128 + pp];
      o0v = fmaf(p3w[j], hp, o0v);
      o1v = fmaf(p3w[64 + j], hp, o1v);
      cv = fmaf(c3w[j], hc, cv);
    }
    const long ip = ((long)n * 128 + pp) * 2;
    out[ip + 0] = i_it[ip + 0] * 4.f + o0v;
    out[ip + 1] = i_it[ip + 1] * 4.f + o1v;
    out[131072 + (long)n * 128 + pp] = cv;
    sig = 1.f / (1.f + expf(-cv));
  }
  __syncthreads();
  if (t < 128) xb[0][pp] = sig;
  __syncthreads();
  if (t < 128) {
    float m = xb[0][pp];
#pragma unroll
    for (int s = 1; s <= 2; s++) {
      m = fmaxf(m, xb[0][(pp + s) & 127]);
      m = fmaxf(m, xb[0][(pp + 128 - s) & 127]);
    }
    out[196608 + (long)n * 128 + pp] = (sig >= m) ? sig : 0.f;
  }
}

extern "C" void kernel_launch(void* const* d_in, const int* in_sizes, int n_in,
                              void* d_out, int out_size, void* d_ws, size_t ws_size,
                              hipStream_t stream) {
  const float* cnn      = (const float*)d_in[0];
  const float* i_it     = (const float*)d_in[1];
  const float* c_it     = (const float*)d_in[2];
  const float* it_cls   = (const float*)d_in[3];
  const int*   ind      = (const int*)d_in[4];
  const float* head_w   = (const float*)d_in[5];
  const float* head_b   = (const float*)d_in[6];
  const float* res_w    = (const float*)d_in[7];
  const float* res_b    = (const float*)d_in[8];
  const float* fusion_w = (const float*)d_in[9];
  const float* fusion_b = (const float*)d_in[10];
  const float* pred1_w  = (const float*)d_in[11];
  const float* pred1_b  = (const float*)d_in[12];
  const float* pred2_w  = (const float*)d_in[13];
  const float* pred2_b  = (const float*)d_in[14];
  const float* pred3_w  = (const float*)d_in[15];
  const float* pred3_b  = (const float*)d_in[16];
  const float* cls1_w   = (const float*)d_in[17];
  const float* cls1_b   = (const float*)d_in[18];
  const float* cls2_w   = (const float*)d_in[19];
  const float* cls2_b   = (const float*)d_in[20];
  const float* cls3_w   = (const float*)d_in[21];
  const float* cls3_b   = (const float*)d_in[22];
  float* ws = (float*)d_ws;
  float* out = (float*)d_out;

  k_repack<<<(int)((REPACK_N + 255) / 256), 256, 0, stream>>>(
      head_w, res_w, fusion_w, pred1_w, cls1_w, pred2_w, cls2_w, ws);

  // chunk polygons by workspace (states only: 131072 floats/poly)
  long avail_f = (long)(ws_size / 4) - OFF_DYN;
  long Cl = avail_f / 131072;
  int C = (int)(Cl < 1 ? 1 : (Cl > 512 ? 512 : Cl));
  float* states = ws + OFF_DYN;

  for (int p0 = 0; p0 < 512; p0 += C) {
    int Cc = (512 - p0 < C) ? (512 - p0) : C;
    k_conv<<<Cc, 512, 0, stream>>>(cnn, i_it, c_it, it_cls, ind,
                                   ws + OFF_CW, head_b, res_b, states, p0);
    k_h1t<<<Cc, 1024, 0, stream>>>(states, ws + OFF_W1H, ws + OFF_FUS, fusion_b,
                                   ws + OFF_W1G, pred1_b, cls1_b,
                                   ws + OFF_W2S, pred2_b, cls2_b,
                                   pred3_w, pred3_b, cls3_w, cls3_b,
                                   i_it, out, p0);
  }
}

// Round 10
// 3944.887 us; speedup vs baseline: 1.6816x; 1.6816x over previous
//
#include <hip/hip_runtime.h>
#include <math.h>

// ---------------- workspace layout (float offsets) ----------------
#define OFF_CW   0L         // conv w [l8][g8][k9][i128][o16]   = 1179648
#define OFF_FUS  1179648L   // fus  w [l8][g8][i128][o32]       = 262144
#define OFF_W1G  1441792L   // W1G  [c256][o512]                = 131072
#define OFF_W1H  1572864L   // W1H  [half2][rc8][i1024][o32]    = 524288
#define OFF_W2   2097152L   // W2   [half2][jg8][i256][o8]      = 32768
#define OFF_GRAW 2129920L   // graw [512][256]                  = 131072
#define OFF_DYN  2260992L   // dynamic: states [C][1024][128]
#define REPACK_N 2129920L

__global__ void k_repack(const float* __restrict__ head_w, const float* __restrict__ res_w,
                         const float* __restrict__ fusion_w,
                         const float* __restrict__ pred1_w, const float* __restrict__ cls1_w,
                         const float* __restrict__ pred2_w, const float* __restrict__ cls2_w,
                         float* __restrict__ ws) {
  long j = (long)blockIdx.x * 256 + threadIdx.x;
  if (j >= REPACK_N) return;
  if (j < OFF_FUS) {                       // CW[l][g][k][i][o16]
    int o = (int)(j & 15); long q = j >> 4;
    int i = (int)(q & 127); long q2 = q >> 7;
    int k = (int)(q2 % 9); long q3 = q2 / 9;
    int g = (int)(q3 & 7), l = (int)(q3 >> 3);
    int og = g * 16 + o;
    float v;
    if (l == 0) v = (i < 67) ? head_w[(og * 67 + i) * 9 + k] : 0.f;
    else        v = res_w[(((l - 1) * 128 + og) * 128 + i) * 9 + k];
    ws[j] = v;
  } else if (j < OFF_W1G) {                // FUS[l][g][i][o32]
    long q = j - OFF_FUS;
    int o = (int)(q & 31), i = (int)((q >> 5) & 127), g = (int)((q >> 12) & 7), l = (int)(q >> 15);
    ws[j] = fusion_w[(long)(g * 32 + o) * 1024 + l * 128 + i];
  } else if (j < OFF_W1H) {                // W1G[c][o]
    long q = j - OFF_W1G; int o = (int)(q & 511); int c = (int)(q >> 9);
    ws[j] = (o < 256) ? pred1_w[(long)o * 1280 + c] : cls1_w[(long)(o - 256) * 1280 + c];
  } else if (j < OFF_W2) {                 // W1H[half][rc][i][o32]
    long q = j - OFF_W1H;
    int o = (int)(q & 31), i = (int)((q >> 5) & 1023), rc = (int)((q >> 15) & 7), hf = (int)(q >> 18);
    int r = rc * 32 + o, c = 256 + i;
    ws[j] = hf ? cls1_w[(long)r * 1280 + c] : pred1_w[(long)r * 1280 + c];
  } else {                                 // W2[half][jg][i][o8]
    long q = j - OFF_W2;
    int o = (int)(q & 7), i = (int)((q >> 3) & 255), jg = (int)((q >> 11) & 7), hf = (int)(q >> 14);
    int jr = jg * 8 + o;
    ws[j] = hf ? cls2_w[jr * 256 + i] : pred2_w[jr * 256 + i];
  }
}

// =============== K1: gather + 8-layer conv + incremental fus + states + graw ===============
// 16 waves: waves 0-7 positions 0-63, waves 8-15 positions 64-127; group g=wv&7 owns conv
// out-ch [16g,16g+16) and fus rows [32g,32g+32). Per (k,i): 1 ds_read_b32 + 16 FMAs +
// 16-float s_load (deep prefetch) -> VALU-bound mix (LDS demand 93 cyc per 128-cyc window).
__global__ __launch_bounds__(1024) __attribute__((amdgpu_waves_per_eu(4)))
void k_conv(const float* __restrict__ cnn, const float* __restrict__ i_it,
            const float* __restrict__ c_it, const float* __restrict__ cls_in,
            const int* __restrict__ ind,
            const float* __restrict__ CW, const float* __restrict__ FUS,
            const float* __restrict__ head_b, const float* __restrict__ res_b,
            float* __restrict__ graw, float* __restrict__ states, int p0) {
  __shared__ float sx[16384];
  __shared__ float part[512];
  const int ln = blockIdx.x, n = p0 + ln, t = threadIdx.x;
  const int po = t & 63;
  const int wv = __builtin_amdgcn_readfirstlane(t >> 6);
  const int g = wv & 7, ph = wv >> 3;
  const int p = po + ph * 64;
  const int ow = g * 16;

  {
    const int p4 = t & 127, og4 = t >> 7;
    const float gx = i_it[((long)n * 128 + p4) * 2 + 0] - 0.5f;
    const float gy = i_it[((long)n * 128 + p4) * 2 + 1] - 0.5f;
    const float fx = floorf(gx), fy = floorf(gy);
    const float wx = gx - fx, wy = gy - fy;
    const int x0 = (int)fx, y0 = (int)fy, x1 = x0 + 1, y1 = y0 + 1;
    const bool vx0 = (x0 >= 0) & (x0 < 128), vx1 = (x1 >= 0) & (x1 < 128);
    const bool vy0 = (y0 >= 0) & (y0 < 128), vy1 = (y1 >= 0) & (y1 < 128);
    const int x0c = min(max(x0, 0), 127), x1c = min(max(x1, 0), 127);
    const int y0c = min(max(y0, 0), 127), y1c = min(max(y1, 0), 127);
    const float w00 = (vx0 && vy0) ? (1.f - wx) * (1.f - wy) : 0.f;
    const float w01 = (vx1 && vy0) ? wx * (1.f - wy) : 0.f;
    const float w10 = (vx0 && vy1) ? (1.f - wx) * wy : 0.f;
    const float w11 = (vx1 && vy1) ? wx * wy : 0.f;
    const long base = (long)ind[n] * 64 * 16384;
    const int a00 = y0c * 128 + x0c, a01 = y0c * 128 + x1c;
    const int a10 = y1c * 128 + x0c, a11 = y1c * 128 + x1c;
    for (int cc = 0; cc < 8; cc++) {
      const int c = og4 * 8 + cc;
      const float* f = cnn + base + (long)c * 16384;
      sx[c * 128 + p4] = f[a00] * w00 + f[a01] * w01 + f[a10] * w10 + f[a11] * w11;
    }
    if (og4 == 0) {
      sx[64 * 128 + p4] = c_it[((long)n * 128 + p4) * 2 + 0] * 4.0f;
      sx[65 * 128 + p4] = c_it[((long)n * 128 + p4) * 2 + 1] * 4.0f;
      sx[66 * 128 + p4] = cls_in[(long)n * 128 + p4];
    }
  }
  for (int idx = t; idx < 61 * 128; idx += 1024) sx[67 * 128 + idx] = 0.f;
  __syncthreads();

  float f0[32];
#pragma unroll
  for (int r = 0; r < 32; r++) f0[r] = 0.f;
  float* st = states + (long)ln * 131072;

  for (int l = 0; l < 8; l++) {
    const int dil = (l >= 6) ? 4 : ((l >= 4) ? 2 : 1);
    const int ni = (l == 0) ? 68 : 128;
    float a[16];
    {
      const float* bsrc = (l == 0) ? (head_b + ow) : (res_b + (l - 1) * 128 + ow);
#pragma unroll
      for (int oo = 0; oo < 16; oo++) a[oo] = bsrc[oo];
    }
    const float* wl = CW + (long)(l * 8 + g) * 18432;
    for (int k = 0; k < 9; k++) {
      const int xa = (p + (k - 4) * dil + 128) & 127;
      const float* wk = wl + k * 2048;
#pragma unroll 4
      for (int i = 0; i < ni; i++) {
        const float xv = sx[i * 128 + xa];
        const float* w = wk + i * 16;
#pragma unroll
        for (int oo = 0; oo < 16; oo++) a[oo] = fmaf(w[oo], xv, a[oo]);
      }
    }
    __syncthreads();
#pragma unroll
    for (int oo = 0; oo < 16; oo++) {
      const int o = ow + oo;
      float v = fmaxf(a[oo], 0.f);
      if (l > 0) v += sx[o * 128 + p];
      sx[o * 128 + p] = v;
      st[(l * 128 + o) * 128 + p] = v;
    }
    __syncthreads();

    const float* fl = FUS + (long)(l * 8 + g) * 4096;
#pragma unroll 4
    for (int i = 0; i < 128; i++) {
      const float xv = sx[i * 128 + p];
      const float* w = fl + i * 32;
#pragma unroll
      for (int r = 0; r < 32; r++) f0[r] = fmaf(w[r], xv, f0[r]);
    }
  }

#pragma unroll
  for (int r = 0; r < 32; r++) {
    float m = f0[r];
#pragma unroll
    for (int s = 32; s > 0; s >>= 1) m = fmaxf(m, __shfl_xor(m, s, 64));
    if (po == 0) part[wv * 32 + r] = m;
  }
  __syncthreads();
  if (t < 256) graw[(long)n * 256 + t] = fmaxf(part[t], part[256 + t]);
}

// =============== K2: per (poly, half): hg prologue + h1 GEMM + head2 + head3 (+NMS) ===============
__global__ __launch_bounds__(1024) __attribute__((amdgpu_waves_per_eu(4)))
void k_h1x(const float* __restrict__ states, const float* __restrict__ graw,
           const float* __restrict__ fus_b, const float* __restrict__ W1G,
           const float* __restrict__ p1b, const float* __restrict__ c1b,
           const float* __restrict__ W1H, const float* __restrict__ W2,
           const float* __restrict__ p2b, const float* __restrict__ c2b,
           const float* __restrict__ p3w, const float* __restrict__ p3b,
           const float* __restrict__ c3w, const float* __restrict__ c3b,
           const float* __restrict__ i_it, float* __restrict__ out, int p0) {
  __shared__ float smem[16384];
  const int b = blockIdx.x, ln = b >> 1, hf = b & 1, n = p0 + ln, t = threadIdx.x;
  const int po = t & 63;
  const int wv = __builtin_amdgcn_readfirstlane(t >> 6);
  const int rc = wv >> 1, ph = wv & 1;
  const int p = po + ph * 64;
  const float* xs = states + (long)ln * 131072;

  if (t < 256) smem[4096 + t] = graw[(long)n * 256 + t] + fus_b[t];
  __syncthreads();
  if (t < 256) {
    const int o = hf * 256 + t;
    float s = hf ? c1b[t] : p1b[t];
    const float* w = W1G + o;
#pragma unroll 8
    for (int c = 0; c < 256; c++) s = fmaf(w[(long)c * 512], smem[4096 + c], s);
    smem[4352 + t] = s;
  }
  __syncthreads();

  float h[32];
#pragma unroll
  for (int r = 0; r < 32; r++) h[r] = 0.f;
  const float* wbase = W1H + ((long)(hf * 8 + rc) << 15);
  float2 px = ((const float2*)xs)[t];
  ((float2*)smem)[t] = px;
  __syncthreads();
  for (int c = 0; c < 64; c++) {
    if (c + 1 < 64) px = ((const float2*)(xs + (long)(c + 1) * 2048))[t];
    const float* xp = smem + (c & 1) * 2048;
    const float* wc = wbase + c * 512;
#pragma unroll 4
    for (int i = 0; i < 16; i++) {
      const float xv = xp[i * 128 + p];
      const float* w = wc + i * 32;
#pragma unroll
      for (int r = 0; r < 32; r++) h[r] = fmaf(w[r], xv, h[r]);
    }
    if (c + 1 < 64) ((float2*)(smem + ((c + 1) & 1) * 2048))[t] = px;
    __syncthreads();
  }
#pragma unroll
  for (int r = 0; r < 32; r++) h[r] = fmaxf(h[r] + smem[4352 + rc * 32 + r], 0.f);
  __syncthreads();

  float aj[8];
#pragma unroll
  for (int jj = 0; jj < 8; jj++) aj[jj] = 0.f;
  const int jg = rc;
  for (int cc = 0; cc < 8; cc++) {
    if (rc == cc) {
#pragma unroll
      for (int r = 0; r < 32; r++) smem[r * 128 + p] = h[r];
    }
    __syncthreads();
    const float* w2 = W2 + ((long)(hf * 8 + jg) * 256 + cc * 32) * 8;
#pragma unroll 4
    for (int i = 0; i < 32; i++) {
      const float xv = smem[i * 128 + p];
      const float* w = w2 + i * 8;
#pragma unroll
      for (int jj = 0; jj < 8; jj++) aj[jj] = fmaf(w[jj], xv, aj[jj]);
    }
    __syncthreads();
  }
#pragma unroll
  for (int jj = 0; jj < 8; jj++) {
    const int j = jg * 8 + jj;
    const float bb = hf ? c2b[j] : p2b[j];
    smem[8192 + j * 128 + p] = fmaxf(aj[jj] + bb, 0.f);
  }
  __syncthreads();

  const int pp = t & 127;
  if (hf == 0) {
    if (t < 128) {
      float o0v = p3b[0], o1v = p3b[1];
      for (int j = 0; j < 64; j++) {
        const float hp = smem[8192 + j * 128 + pp];
        o0v = fmaf(p3w[j], hp, o0v);
        o1v = fmaf(p3w[64 + j], hp, o1v);
      }
      const long ip = ((long)n * 128 + pp) * 2;
      out[ip + 0] = i_it[ip + 0] * 4.f + o0v;
      out[ip + 1] = i_it[ip + 1] * 4.f + o1v;
    }
  } else {
    float sig = 0.f;
    if (t < 128) {
      float cv = c3b[0];
      for (int j = 0; j < 64; j++) cv = fmaf(c3w[j], smem[8192 + j * 128 + pp], cv);
      out[131072 + (long)n * 128 + pp] = cv;
      sig = 1.f / (1.f + expf(-cv));
    }
    __syncthreads();
    if (t < 128) smem[pp] = sig;
    __syncthreads();
    if (t < 128) {
      float m = smem[pp];
#pragma unroll
      for (int s = 1; s <= 2; s++) {
        m = fmaxf(m, smem[(pp + s) & 127]);
        m = fmaxf(m, smem[(pp + 128 - s) & 127]);
      }
      out[196608 + (long)n * 128 + pp] = (sig >= m) ? sig : 0.f;
    }
  }
}

extern "C" void kernel_launch(void* const* d_in, const int* in_sizes, int n_in,
                              void* d_out, int out_size, void* d_ws, size_t ws_size,
                              hipStream_t stream) {
  const float* cnn      = (const float*)d_in[0];
  const float* i_it     = (const float*)d_in[1];
  const float* c_it     = (const float*)d_in[2];
  const float* it_cls   = (const float*)d_in[3];
  const int*   ind      = (const int*)d_in[4];
  const float* head_w   = (const float*)d_in[5];
  const float* head_b   = (const float*)d_in[6];
  const float* res_w    = (const float*)d_in[7];
  const float* res_b    = (const float*)d_in[8];
  const float* fusion_w = (const float*)d_in[9];
  const float* fusion_b = (const float*)d_in[10];
  const float* pred1_w  = (const float*)d_in[11];
  const float* pred1_b  = (const float*)d_in[12];
  const float* pred2_w  = (const float*)d_in[13];
  const float* pred2_b  = (const float*)d_in[14];
  const float* pred3_w  = (const float*)d_in[15];
  const float* pred3_b  = (const float*)d_in[16];
  const float* cls1_w   = (const float*)d_in[17];
  const float* cls1_b   = (const float*)d_in[18];
  const float* cls2_w   = (const float*)d_in[19];
  const float* cls2_b   = (const float*)d_in[20];
  const float* cls3_w   = (const float*)d_in[21];
  const float* cls3_b   = (const float*)d_in[22];
  float* ws = (float*)d_ws;
  float* out = (float*)d_out;

  k_repack<<<(int)((REPACK_N + 255) / 256), 256, 0, stream>>>(
      head_w, res_w, fusion_w, pred1_w, cls1_w, pred2_w, cls2_w, ws);

  long avail_f = (long)(ws_size / 4) - OFF_DYN;
  long Cl = avail_f / 131072;
  int C = (int)(Cl < 1 ? 1 : (Cl > 256 ? 256 : Cl));
  float* states = ws + OFF_DYN;

  for (int p0 = 0; p0 < 512; p0 += C) {
    int Cc = (512 - p0 < C) ? (512 - p0) : C;
    k_conv<<<Cc, 1024, 0, stream>>>(cnn, i_it, c_it, it_cls, ind,
                                    ws + OFF_CW, ws + OFF_FUS, head_b, res_b,
                                    ws + OFF_GRAW, states, p0);
    k_h1x<<<2 * Cc, 1024, 0, stream>>>(states, ws + OFF_GRAW, fusion_b, ws + OFF_W1G,
                                       pred1_b, cls1_b, ws + OFF_W1H, ws + OFF_W2,
                                       pred2_b, cls2_b,
                                       pred3_w, pred3_b, cls3_w, cls3_b,
                                       i_it, out, p0);
  }
}

// Round 11
// 3391.483 us; speedup vs baseline: 1.9560x; 1.1632x over previous
//
#include <hip/hip_runtime.h>
#include <math.h>

// ---------------- workspace layout (float offsets) ----------------
#define OFF_CWS  0L         // conv w  [l8][wv16][k9][i128][o8]  = 1179648
#define OFF_FWS  1179648L   // fus  w  [l8][wv16][i128][o16]     = 262144
#define OFF_W1G  1441792L   // W1G  [c256][o512]                 = 131072
#define OFF_W1H  1572864L   // W1H  [wv16][i1024][o32]           = 524288
#define OFF_W2S  2097152L   // W2S  [c4][wv16][i128][o4]         = 32768
#define OFF_GRAW 2129920L   // graw [512][256]                   = 131072
#define OFF_HG   2260992L   // hg   [512][512]                   = 262144
#define OFF_DYN  2523136L   // dynamic: states [C][1024][128]
#define REPACK_N 2129920L

__global__ void k_repack(const float* __restrict__ head_w, const float* __restrict__ res_w,
                         const float* __restrict__ fusion_w,
                         const float* __restrict__ pred1_w, const float* __restrict__ cls1_w,
                         const float* __restrict__ pred2_w, const float* __restrict__ cls2_w,
                         float* __restrict__ ws) {
  long j = (long)blockIdx.x * 256 + threadIdx.x;
  if (j >= REPACK_N) return;
  if (j < OFF_FWS) {                       // CWS[l][wv][k][i][o8]
    int o = (int)(j & 7), i = (int)((j >> 3) & 127);
    long q = j >> 10; int k = (int)(q % 9); int wv = (int)((q / 9) & 15); int l = (int)(q / 144);
    int og = wv * 8 + o;
    float v;
    if (l == 0) v = (i < 67) ? head_w[(og * 67 + i) * 9 + k] : 0.f;
    else        v = res_w[(((l - 1) * 128 + og) * 128 + i) * 9 + k];
    ws[j] = v;
  } else if (j < OFF_W1G) {                // FWS[l][wv][i][o16]
    long q = j - OFF_FWS;
    int o = (int)(q & 15), i = (int)((q >> 4) & 127), wv = (int)((q >> 11) & 15), l = (int)(q >> 15);
    ws[j] = fusion_w[(long)(wv * 16 + o) * 1024 + l * 128 + i];
  } else if (j < OFF_W1H) {                // W1G[c][o]
    long q = j - OFF_W1G; int o = (int)(q & 511); int c = (int)(q >> 9);
    ws[j] = (o < 256) ? pred1_w[(long)o * 1280 + c] : cls1_w[(long)(o - 256) * 1280 + c];
  } else if (j < OFF_W2S) {                // W1H[wv][i][o32]
    long q = j - OFF_W1H;
    int o = (int)(q & 31), i = (int)((q >> 5) & 1023), wv = (int)(q >> 15);
    int ho = wv * 32 + o, c = 256 + i;
    ws[j] = (ho < 256) ? pred1_w[(long)ho * 1280 + c] : cls1_w[(long)(ho - 256) * 1280 + c];
  } else {                                 // W2S[c][wv][i][o4]
    long q = j - OFF_W2S;
    int o = (int)(q & 3), i = (int)((q >> 2) & 127), wv = (int)((q >> 9) & 15), c = (int)(q >> 13);
    int jg = wv * 4 + o;
    ws[j] = (c < 2) ? pred2_w[jg * 256 + c * 128 + i] : cls2_w[jg * 256 + (c - 2) * 128 + i];
  }
}

// =============== K1: gather + 8-layer conv chain + incremental fus + states (R6 structure) ===============
// 16 waves x 8 out-ch; lane po owns positions {po, po+64} -> paired reads merge to ds_read2_b32.
// Weights: wave-uniform dwordx8 s_load streams; unroll 8 => 64 SGPRs of prefetch in flight.
__global__ __launch_bounds__(1024) __attribute__((amdgpu_waves_per_eu(4)))
void k_conv(const float* __restrict__ cnn, const float* __restrict__ i_it,
            const float* __restrict__ c_it, const float* __restrict__ cls_in,
            const int* __restrict__ ind,
            const float* __restrict__ CWS, const float* __restrict__ FWS,
            const float* __restrict__ head_b, const float* __restrict__ res_b,
            float* __restrict__ graw, float* __restrict__ states, int p0) {
  __shared__ float sx[16384];    // [128 ch][128 pos] 64 KB
  const int ln = blockIdx.x, n = p0 + ln, t = threadIdx.x;
  const int po = t & 63;
  const int wv = __builtin_amdgcn_readfirstlane(t >> 6);
  const int ob = wv * 8;

  // ---- bilinear gather ----
  {
    const int p4 = t & 127, og4 = t >> 7;
    const float gx = i_it[((long)n * 128 + p4) * 2 + 0] - 0.5f;
    const float gy = i_it[((long)n * 128 + p4) * 2 + 1] - 0.5f;
    const float fx = floorf(gx), fy = floorf(gy);
    const float wx = gx - fx, wy = gy - fy;
    const int x0 = (int)fx, y0 = (int)fy, x1 = x0 + 1, y1 = y0 + 1;
    const bool vx0 = (x0 >= 0) & (x0 < 128), vx1 = (x1 >= 0) & (x1 < 128);
    const bool vy0 = (y0 >= 0) & (y0 < 128), vy1 = (y1 >= 0) & (y1 < 128);
    const int x0c = min(max(x0, 0), 127), x1c = min(max(x1, 0), 127);
    const int y0c = min(max(y0, 0), 127), y1c = min(max(y1, 0), 127);
    const float w00 = (vx0 && vy0) ? (1.f - wx) * (1.f - wy) : 0.f;
    const float w01 = (vx1 && vy0) ? wx * (1.f - wy) : 0.f;
    const float w10 = (vx0 && vy1) ? (1.f - wx) * wy : 0.f;
    const float w11 = (vx1 && vy1) ? wx * wy : 0.f;
    const long base = (long)ind[n] * 64 * 16384;
    const int a00 = y0c * 128 + x0c, a01 = y0c * 128 + x1c;
    const int a10 = y1c * 128 + x0c, a11 = y1c * 128 + x1c;
    for (int cc = 0; cc < 8; cc++) {
      const int c = og4 * 8 + cc;
      const float* f = cnn + base + (long)c * 16384;
      sx[c * 128 + p4] = f[a00] * w00 + f[a01] * w01 + f[a10] * w10 + f[a11] * w11;
    }
    if (og4 == 0) {
      sx[64 * 128 + p4] = c_it[((long)n * 128 + p4) * 2 + 0] * 4.0f;
      sx[65 * 128 + p4] = c_it[((long)n * 128 + p4) * 2 + 1] * 4.0f;
      sx[66 * 128 + p4] = cls_in[(long)n * 128 + p4];
    }
  }
  for (int idx = t; idx < 61 * 128; idx += 1024) sx[67 * 128 + idx] = 0.f;
  __syncthreads();

  float f0[16], f1[16];
#pragma unroll
  for (int r = 0; r < 16; r++) { f0[r] = 0.f; f1[r] = 0.f; }
  float* st = states + (long)ln * 131072;

  for (int l = 0; l < 8; l++) {
    const int dil = (l >= 6) ? 4 : ((l >= 4) ? 2 : 1);
    const int ni = (l == 0) ? 68 : 128;    // head conv rows >=67 are zero
    float a0[8], a1[8];
    {
      const float* bsrc = (l == 0) ? (head_b + ob) : (res_b + (l - 1) * 128 + ob);
#pragma unroll
      for (int oo = 0; oo < 8; oo++) { a0[oo] = bsrc[oo]; a1[oo] = a0[oo]; }
    }
    const float* wl = CWS + (long)(l * 16 + wv) * 9216;
    for (int k = 0; k < 9; k++) {
      const int xa0 = (po + (k - 4) * dil + 128) & 127;
      const int xa1 = xa0 ^ 64;
      const float* wk = wl + k * 1024;
#pragma unroll 8
      for (int i = 0; i < ni; i++) {
        const float xv0 = sx[i * 128 + xa0];
        const float xv1 = sx[i * 128 + xa1];
        const float* w = wk + i * 8;       // wave-uniform -> s_load_dwordx8
#pragma unroll
        for (int oo = 0; oo < 8; oo++) {
          a0[oo] = fmaf(w[oo], xv0, a0[oo]);
          a1[oo] = fmaf(w[oo], xv1, a1[oo]);
        }
      }
    }
    __syncthreads();
#pragma unroll
    for (int oo = 0; oo < 8; oo++) {
      const int o = ob + oo;
      float v0 = fmaxf(a0[oo], 0.f), v1 = fmaxf(a1[oo], 0.f);
      if (l > 0) { v0 += sx[o * 128 + po]; v1 += sx[o * 128 + po + 64]; }
      sx[o * 128 + po] = v0;
      sx[o * 128 + po + 64] = v1;
      st[(l * 128 + o) * 128 + po] = v0;
      st[(l * 128 + o) * 128 + po + 64] = v1;
    }
    __syncthreads();

    // ---- incremental fusion for slot l (weights via s_load, deep prefetch) ----
    const float* fl = FWS + (long)(l * 16 + wv) * 2048;
#pragma unroll 8
    for (int i = 0; i < 128; i++) {
      const float xv0 = sx[i * 128 + po];
      const float xv1 = sx[i * 128 + po + 64];
      const float* w = fl + i * 16;        // wave-uniform -> s_load
#pragma unroll
      for (int r = 0; r < 16; r++) {
        f0[r] = fmaf(w[r], xv0, f0[r]);
        f1[r] = fmaf(w[r], xv1, f1[r]);
      }
    }
  }

  // ---- fusion max over all 128 positions -> graw ----
#pragma unroll
  for (int r = 0; r < 16; r++) {
    float m = fmaxf(f0[r], f1[r]);
#pragma unroll
    for (int s = 32; s > 0; s >>= 1) m = fmaxf(m, __shfl_xor(m, s, 64));
    if (po == 0) graw[(long)n * 256 + wv * 16 + r] = m;
  }
}

// =============== K_hg: hg[n][o] = bias + W1G[:,o].(graw+fus_b) ===============
__global__ __launch_bounds__(512)
void k_hg(const float* __restrict__ graw, const float* __restrict__ fus_b,
          const float* __restrict__ W1G, const float* __restrict__ p1b, const float* __restrict__ c1b,
          float* __restrict__ hg, int p0) {
  __shared__ float sg[256];
  const int n = p0 + blockIdx.x, t = threadIdx.x;
  if (t < 256) sg[t] = graw[(long)n * 256 + t] + fus_b[t];
  __syncthreads();
  float s = (t < 256) ? p1b[t] : c1b[t - 256];
  const float* w = W1G + t;
#pragma unroll 8
  for (int c = 0; c < 256; c++) s = fmaf(w[(long)c * 512], sg[c], s);
  hg[(long)n * 512 + t] = s;
}

// =============== K2: h1 GEMM (regs) + pred2/cls2 + pred3/cls3 + NMS, fused (R6 structure) ===============
__global__ __launch_bounds__(1024) __attribute__((amdgpu_waves_per_eu(4)))
void k_h1t(const float* __restrict__ states, const float* __restrict__ W1H,
           const float* __restrict__ hg, const float* __restrict__ W2S,
           const float* __restrict__ p2b, const float* __restrict__ c2b,
           const float* __restrict__ p3w, const float* __restrict__ p3b,
           const float* __restrict__ c3w, const float* __restrict__ c3b,
           const float* __restrict__ i_it, float* __restrict__ out, int p0) {
  __shared__ float xb[2][2048];   // states staging, 16 rows x 128 pos dbuf (16 KB)
  __shared__ float hx[16384];     // h1 chunk / h2 buffer (64 KB)
  const int ln = blockIdx.x, n = p0 + ln, t = threadIdx.x;
  const int po = t & 63;
  const int wv = __builtin_amdgcn_readfirstlane(t >> 6);
  const float* xs = states + (long)ln * 131072;

  // ---- phase 1: h1 = relu(W1H @ states + hg); wave wv owns 32 h1 rows ----
  float h0[32], h1v[32];
#pragma unroll
  for (int r = 0; r < 32; r++) { h0[r] = 0.f; h1v[r] = 0.f; }
  const float* wbase = W1H + (long)wv * 32768;
  float2 px = ((const float2*)xs)[t];
  int buf = 0;
  for (int c = 0; c < 64; c++) {
    ((float2*)xb[buf])[t] = px;
    __syncthreads();
    if (c + 1 < 64) px = ((const float2*)(xs + (long)(c + 1) * 2048))[t];
    const float* wc = wbase + c * 512;
#pragma unroll 4
    for (int i = 0; i < 16; i++) {
      const float xv0 = xb[buf][i * 128 + po];          // pairs -> ds_read2
      const float xv1 = xb[buf][i * 128 + po + 64];
      const float* w = wc + i * 32;                     // wave-uniform -> s_load
#pragma unroll
      for (int r = 0; r < 32; r++) {
        h0[r] = fmaf(w[r], xv0, h0[r]);
        h1v[r] = fmaf(w[r], xv1, h1v[r]);
      }
    }
    __syncthreads();
    buf ^= 1;
  }
  {
    const float* hgp = hg + (long)n * 512 + wv * 32;
#pragma unroll
    for (int r = 0; r < 32; r++) {
      h0[r] = fmaxf(h0[r] + hgp[r], 0.f);
      h1v[r] = fmaxf(h1v[r] + hgp[r], 0.f);
    }
  }

  // ---- phase 2: pred2/cls2 over 4 chunks of 128 h1 rows ----
  float ap0[4], ap1[4], ac0[4], ac1[4];
#pragma unroll
  for (int jj = 0; jj < 4; jj++) { ap0[jj] = 0.f; ap1[jj] = 0.f; ac0[jj] = 0.f; ac1[jj] = 0.f; }
#pragma unroll
  for (int c = 0; c < 4; c++) {
    __syncthreads();
    if ((wv >> 2) == c) {
#pragma unroll
      for (int r = 0; r < 32; r++) {
        const int row = (wv & 3) * 32 + r;
        hx[row * 128 + po] = h0[r];
        hx[row * 128 + po + 64] = h1v[r];
      }
    }
    __syncthreads();
    const float* w2 = W2S + (long)(c * 16 + wv) * 512;
#pragma unroll 4
    for (int i = 0; i < 128; i++) {
      const float xv0 = hx[i * 128 + po];
      const float xv1 = hx[i * 128 + po + 64];
      const float* w = w2 + i * 4;
      if (c < 2) {
#pragma unroll
        for (int jj = 0; jj < 4; jj++) {
          ap0[jj] = fmaf(w[jj], xv0, ap0[jj]);
          ap1[jj] = fmaf(w[jj], xv1, ap1[jj]);
        }
      } else {
#pragma unroll
        for (int jj = 0; jj < 4; jj++) {
          ac0[jj] = fmaf(w[jj], xv0, ac0[jj]);
          ac1[jj] = fmaf(w[jj], xv1, ac1[jj]);
        }
      }
    }
  }
  __syncthreads();
#pragma unroll
  for (int jj = 0; jj < 4; jj++) {   // h2 rows: j<64 pred2, j>=64 cls2
    const int j = wv * 4 + jj;
    hx[j * 128 + po] = fmaxf(ap0[jj] + p2b[j], 0.f);
    hx[j * 128 + po + 64] = fmaxf(ap1[jj] + p2b[j], 0.f);
    hx[(64 + j) * 128 + po] = fmaxf(ac0[jj] + c2b[j], 0.f);
    hx[(64 + j) * 128 + po + 64] = fmaxf(ac1[jj] + c2b[j], 0.f);
  }
  __syncthreads();

  // ---- phase 3: pred3/cls3 + outputs + NMS ----
  float sig = 0.f;
  const int pp = t & 127;
  if (t < 128) {
    float o0v = p3b[0], o1v = p3b[1], cv = c3b[0];
    for (int j = 0; j < 64; j++) {
      const float hp = hx[j * 128 + pp];
      const float hc = hx[(64 + j) * 128 + pp];
      o0v = fmaf(p3w[j], hp, o0v);
      o1v = fmaf(p3w[64 + j], hp, o1v);
      cv = fmaf(c3w[j], hc, cv);
    }
    const long ip = ((long)n * 128 + pp) * 2;
    out[ip + 0] = i_it[ip + 0] * 4.f + o0v;
    out[ip + 1] = i_it[ip + 1] * 4.f + o1v;
    out[131072 + (long)n * 128 + pp] = cv;
    sig = 1.f / (1.f + expf(-cv));
  }
  __syncthreads();
  if (t < 128) xb[0][pp] = sig;
  __syncthreads();
  if (t < 128) {
    float m = xb[0][pp];
#pragma unroll
    for (int s = 1; s <= 2; s++) {
      m = fmaxf(m, xb[0][(pp + s) & 127]);
      m = fmaxf(m, xb[0][(pp + 128 - s) & 127]);
    }
    out[196608 + (long)n * 128 + pp] = (sig >= m) ? sig : 0.f;
  }
}

extern "C" void kernel_launch(void* const* d_in, const int* in_sizes, int n_in,
                              void* d_out, int out_size, void* d_ws, size_t ws_size,
                              hipStream_t stream) {
  const float* cnn      = (const float*)d_in[0];
  const float* i_it     = (const float*)d_in[1];
  const float* c_it     = (const float*)d_in[2];
  const float* it_cls   = (const float*)d_in[3];
  const int*   ind      = (const int*)d_in[4];
  const float* head_w   = (const float*)d_in[5];
  const float* head_b   = (const float*)d_in[6];
  const float* res_w    = (const float*)d_in[7];
  const float* res_b    = (const float*)d_in[8];
  const float* fusion_w = (const float*)d_in[9];
  const float* fusion_b = (const float*)d_in[10];
  const float* pred1_w  = (const float*)d_in[11];
  const float* pred1_b  = (const float*)d_in[12];
  const float* pred2_w  = (const float*)d_in[13];
  const float* pred2_b  = (const float*)d_in[14];
  const float* pred3_w  = (const float*)d_in[15];
  const float* pred3_b  = (const float*)d_in[16];
  const float* cls1_w   = (const float*)d_in[17];
  const float* cls1_b   = (const float*)d_in[18];
  const float* cls2_w   = (const float*)d_in[19];
  const float* cls2_b   = (const float*)d_in[20];
  const float* cls3_w   = (const float*)d_in[21];
  const float* cls3_b   = (const float*)d_in[22];
  float* ws = (float*)d_ws;
  float* out = (float*)d_out;

  k_repack<<<(int)((REPACK_N + 255) / 256), 256, 0, stream>>>(
      head_w, res_w, fusion_w, pred1_w, cls1_w, pred2_w, cls2_w, ws);

  // chunk polygons; clamp to 256 for balanced full-machine rounds
  long avail_f = (long)(ws_size / 4) - OFF_DYN;
  long Cl = avail_f / 131072;
  int C = (int)(Cl < 1 ? 1 : (Cl > 256 ? 256 : Cl));
  float* states = ws + OFF_DYN;

  for (int p0 = 0; p0 < 512; p0 += C) {
    int Cc = (512 - p0 < C) ? (512 - p0) : C;
    k_conv<<<Cc, 1024, 0, stream>>>(cnn, i_it, c_it, it_cls, ind,
                                    ws + OFF_CWS, ws + OFF_FWS, head_b, res_b,
                                    ws + OFF_GRAW, states, p0);
    k_hg<<<Cc, 512, 0, stream>>>(ws + OFF_GRAW, fusion_b, ws + OFF_W1G,
                                 pred1_b, cls1_b, ws + OFF_HG, p0);
    k_h1t<<<Cc, 1024, 0, stream>>>(states, ws + OFF_W1H, ws + OFF_HG, ws + OFF_W2S,
                                   pred2_b, cls2_b, pred3_w, pred3_b, cls3_w, cls3_b,
                                   i_it, out, p0);
  }
}